// Round 11
// baseline (120.359 us; speedup 1.0000x reference)
//
#include <hip/hip_runtime.h>
#include <stdint.h>
#include <stddef.h>

#define SS 512
#define HID 1024
#define NHEADS 12
#define HSZ 64
#define NPROJ 1536
#define NEG_INF 1000000000000.0f

typedef __attribute__((ext_vector_type(4))) float f32x4;
typedef __attribute__((ext_vector_type(8))) __bf16 bf16x8;
typedef __attribute__((ext_vector_type(4))) unsigned short us4;

typedef __attribute__((address_space(1))) unsigned char gu8;
typedef __attribute__((address_space(3))) unsigned char lu8;

static __device__ __forceinline__ void gld16(const void* g, void* l) {
  __builtin_amdgcn_global_load_lds((gu8*)(g), (lu8*)(l), 16, 0, 0);
}

static __device__ __forceinline__ unsigned short f2bf(float f) {
  union { float f; unsigned u; } x; x.f = f;
  unsigned r = x.u + 0x7fffu + ((x.u >> 16) & 1u);
  return (unsigned short)(r >> 16);
}

// ---- merged prep: [0,64) sincos table | [64,4160) x->bf16 | [4160,5696) W^T->bf16
__global__ __launch_bounds__(256) void k_prep(
    const float4* __restrict__ x, const float* __restrict__ W,
    float2* __restrict__ tab, us4* __restrict__ xb, unsigned short* __restrict__ wbt) {
  __shared__ float t[32][33];
  const int bid = blockIdx.x;
  const int tid = threadIdx.x;
  if (bid < 64) {
    int tt = bid * 256 + tid;
    int s = tt >> 5, i = tt & 31;
    float rate = powf(10000.0f, -(float)i / 32.0f);
    float sv, cv;
    sincosf((float)s * rate, &sv, &cv);
    tab[tt] = make_float2(sv, cv);
  } else if (bid < 64 + 4096) {
    int i = (bid - 64) * 256 + tid;
    float4 v = x[i];
    us4 o;
    o[0] = f2bf(v.x); o[1] = f2bf(v.y); o[2] = f2bf(v.z); o[3] = f2bf(v.w);
    xb[i] = o;
  } else {
    int flat = bid - (64 + 4096);
    int n0 = (flat % 48) * 32, k0 = (flat / 48) * 32;
    int tx = tid & 31, ty = tid >> 5;
#pragma unroll
    for (int i = 0; i < 4; ++i)
      t[ty + i * 8][tx] = W[(k0 + ty + i * 8) * NPROJ + n0 + tx];
    __syncthreads();
#pragma unroll
    for (int i = 0; i < 4; ++i)
      wbt[(n0 + ty + i * 8) * HID + (k0 + tx)] = f2bf(t[tx][ty + i * 8]);
  }
}

// ---- GEMM1 (R5-exact): M=128,N=96,BK=64; grid (32,16); dbuf + counted vmcnt.
__global__ __launch_bounds__(256) void k_proj(
    const unsigned short* __restrict__ xb, const unsigned short* __restrict__ wbt,
    const float* __restrict__ bias, const float2* __restrict__ tab,
    unsigned short* __restrict__ qo, unsigned short* __restrict__ ko) {
  __shared__ __align__(16) unsigned short lA[2][128 * 64];
  __shared__ __align__(16) unsigned short lB[2][96 * 64];
  const int tid = threadIdx.x;
  const int lane = tid & 63, w = tid >> 6;
  const int wm = w >> 1, wn = w & 1;
  const int m0 = blockIdx.x * 128, n0 = blockIdx.y * 96;

  const char* aptr[4]; const char* bptr[3];
  int adst[4], bdst[3];
#pragma unroll
  for (int c = 0; c < 4; ++c) {
    int lin = (w * 4 + c) * 1024 + lane * 16;
    int row = lin >> 7, cb = lin & 127;
    aptr[c] = (const char*)(xb + (size_t)(m0 + row) * HID) + (cb ^ ((row & 7) << 4));
    adst[c] = (w * 4 + c) * 1024;
  }
#pragma unroll
  for (int c = 0; c < 3; ++c) {
    int lin = (w * 3 + c) * 1024 + lane * 16;
    int row = lin >> 7, cb = lin & 127;
    bptr[c] = (const char*)(wbt + (size_t)(n0 + row) * HID) + (cb ^ ((row & 7) << 4));
    bdst[c] = (w * 3 + c) * 1024;
  }

  f32x4 acc[3][4];
#pragma unroll
  for (int a = 0; a < 3; ++a)
#pragma unroll
    for (int b = 0; b < 4; ++b)
      acc[a][b] = (f32x4)(0.0f);

#define STAGE(buf, kt)                                                      \
  do {                                                                      \
    _Pragma("unroll") for (int c = 0; c < 4; ++c)                           \
        gld16(aptr[c] + (kt) * 128, (char*)(&lA[(buf)][0]) + adst[c]);      \
    _Pragma("unroll") for (int c = 0; c < 3; ++c)                           \
        gld16(bptr[c] + (kt) * 128, (char*)(&lB[(buf)][0]) + bdst[c]);      \
  } while (0)

  __builtin_amdgcn_sched_barrier(0);
  STAGE(0, 0);

  for (int kt = 0; kt < 16; ++kt) {
    const int cur = kt & 1;
    if (kt < 15) {
      STAGE(cur ^ 1, kt + 1);
      asm volatile("s_waitcnt vmcnt(7)" ::: "memory");
    } else {
      asm volatile("s_waitcnt vmcnt(0)" ::: "memory");
    }
    __builtin_amdgcn_s_barrier();
#pragma unroll
    for (int ks = 0; ks < 2; ++ks) {
      bf16x8 af[3], bf[4];
      const int kb = ks * 64 + (lane >> 4) * 16;
#pragma unroll
      for (int a = 0; a < 3; ++a) {
        int row = wn * 48 + a * 16 + (lane & 15);
        af[a] = *(const bf16x8*)((const char*)(&lB[cur][0]) + row * 128 + (kb ^ ((row & 7) << 4)));
      }
#pragma unroll
      for (int b = 0; b < 4; ++b) {
        int row = wm * 64 + b * 16 + (lane & 15);
        bf[b] = *(const bf16x8*)((const char*)(&lA[cur][0]) + row * 128 + (kb ^ ((row & 7) << 4)));
      }
#pragma unroll
      for (int a = 0; a < 3; ++a)
#pragma unroll
        for (int b = 0; b < 4; ++b)
          acc[a][b] = __builtin_amdgcn_mfma_f32_16x16x32_bf16(af[a], bf[b], acc[a][b], 0, 0, 0);
    }
    asm volatile("s_waitcnt lgkmcnt(0)" ::: "memory");
    __builtin_amdgcn_s_barrier();
  }
#undef STAGE
  __builtin_amdgcn_sched_barrier(0);

#pragma unroll
  for (int a = 0; a < 3; ++a) {
    const int nq = n0 + wn * 48 + a * 16 + (lane >> 4) * 4;
    const float4 bv = *(const float4*)(bias + nq);
    const int d = nq & 63;
    const int h = nq >> 7;
    unsigned short* base = ((nq >> 6) & 1) ? ko : qo;
#pragma unroll
    for (int b = 0; b < 4; ++b) {
      const int mrow = m0 + wm * 64 + b * 16 + (lane & 15);
      const int s = mrow & (SS - 1);
      const int bidx = mrow >> 9;
      const float2* tp = tab + s * 32 + (d & 31);
      const float4 ta = *(const float4*)(tp);
      const float4 tb = *(const float4*)(tp + 2);
      float v0 = acc[a][b][0] + bv.x;
      float v1 = acc[a][b][1] + bv.y;
      float v2 = acc[a][b][2] + bv.z;
      float v3 = acc[a][b][3] + bv.w;
      float o0 = v0 * ta.y - v1 * ta.x;
      float o1 = v1 * ta.w + v0 * ta.z;
      float o2 = v2 * tb.y - v3 * tb.x;
      float o3 = v3 * tb.w + v2 * tb.z;
      us4 pk;
      pk[0] = f2bf(o0); pk[1] = f2bf(o1); pk[2] = f2bf(o2); pk[3] = f2bf(o3);
      *(us4*)(base + ((size_t)(bidx * NHEADS + h) * SS + s) * HSZ + d) = pk;
    }
  }
}

// ---- GEMM2: R5 structure + fully-causal-tile skip (v=0 through identical store path).
__global__ __launch_bounds__(256) void k_logits(
    const unsigned short* __restrict__ q, const unsigned short* __restrict__ kk,
    const float* __restrict__ mask, float* __restrict__ out) {
  const int tid = threadIdx.x;
  const int lane = tid & 63, w = tid >> 6;
  const int bh = blockIdx.y;
  const int b = bh / NHEADS;
  const int m0 = (blockIdx.x >> 2) * 128, n0 = (blockIdx.x & 3) * 128;
  const char* qbase = (const char*)(q + (size_t)bh * SS * HSZ);
  const char* kbase = (const char*)(kk + (size_t)bh * SS * HSZ);
  const bool full_masked = (n0 + 128 <= m0);

  int mrow[4], nrow[4];
#pragma unroll
  for (int i = 0; i < 4; ++i) {
    mrow[i] = m0 + (w >> 1) * 64 + i * 16 + (lane & 15);
    nrow[i] = n0 + (w & 1) * 64 + i * 16 + (lane & 15);
  }

  f32x4 acc[4][4];  // [ni][mi]
#pragma unroll
  for (int a = 0; a < 4; ++a)
#pragma unroll
    for (int bb = 0; bb < 4; ++bb)
      acc[a][bb] = (f32x4)(0.0f);

  if (!full_masked) {
#pragma unroll
    for (int ks = 0; ks < 2; ++ks) {
      const int kboff = ks * 64 + (lane >> 4) * 16;
      bf16x8 kf[4], qf[4];
#pragma unroll
      for (int i = 0; i < 4; ++i)
        kf[i] = *(const bf16x8*)(kbase + (size_t)nrow[i] * 128 + kboff);
#pragma unroll
      for (int i = 0; i < 4; ++i)
        qf[i] = *(const bf16x8*)(qbase + (size_t)mrow[i] * 128 + kboff);
#pragma unroll
      for (int ni = 0; ni < 4; ++ni)
#pragma unroll
        for (int mi = 0; mi < 4; ++mi)
          acc[ni][mi] = __builtin_amdgcn_mfma_f32_16x16x32_bf16(kf[ni], qf[mi], acc[ni][mi], 0, 0, 0);
    }
  }

#pragma unroll
  for (int mi = 0; mi < 4; ++mi) {
    const int m = mrow[mi];
    const float mr = mask[b * SS + m];
    float* orow = out + ((size_t)bh * SS + m) * SS;
#pragma unroll
    for (int ni = 0; ni < 4; ++ni) {
      const int nb = n0 + (w & 1) * 64 + ni * 16 + (lane >> 4) * 4;
      const float4 mc = *(const float4*)(mask + b * SS + nb);
      f32x4 res;
#pragma unroll
      for (int r = 0; r < 4; ++r) {
        float v = acc[ni][mi][r];
        const float mcv = (r == 0) ? mc.x : (r == 1) ? mc.y : (r == 2) ? mc.z : mc.w;
        v = v * mr - NEG_INF * (1.0f - mr);
        v = v * mcv - NEG_INF * (1.0f - mcv);
        if (m > nb + r) v -= NEG_INF;
        res[r] = v * 0.125f;
      }
      *(f32x4*)(orow + nb) = res;
    }
  }
}

extern "C" void kernel_launch(void* const* d_in, const int* in_sizes, int n_in,
                              void* d_out, int out_size, void* d_ws, size_t ws_size,
                              hipStream_t stream) {
  const float* x = (const float*)d_in[0];
  const float* mask = (const float*)d_in[1];
  const float* W = (const float*)d_in[2];
  const float* bias = (const float*)d_in[3];
  float* out = (float*)d_out;

  char* ws = (char*)d_ws;
  float2* tab = (float2*)ws;                                               // 128 KB
  unsigned short* xb = (unsigned short*)(ws + 131072);                     // 8 MB
  unsigned short* wbt = (unsigned short*)(ws + 131072 + 8388608);          // 3 MB
  unsigned short* qo = (unsigned short*)(ws + 131072 + 8388608 + 3145728); // 6.29 MB
  unsigned short* ko = (unsigned short*)(ws + 131072 + 8388608 + 3145728 + 6291456);

  k_prep<<<dim3(64 + 4096 + 1536), dim3(256), 0, stream>>>(
      (const float4*)x, W, tab, (us4*)xb, wbt);
  k_proj<<<dim3(32, 16), dim3(256), 0, stream>>>(xb, wbt, bias, tab, qo, ko);
  // DIAGNOSTIC: k_logits launched 3x (idempotent). dur = base + 2*t_logits.
  k_logits<<<dim3(16, 96), dim3(256), 0, stream>>>(qo, ko, mask, out);
  k_logits<<<dim3(16, 96), dim3(256), 0, stream>>>(qo, ko, mask, out);
  k_logits<<<dim3(16, 96), dim3(256), 0, stream>>>(qo, ko, mask, out);
}

// Round 12
// 60.535 us; speedup vs baseline: 1.9882x; 1.9882x over previous
//
#include <hip/hip_runtime.h>
#include <stdint.h>
#include <stddef.h>

#define SS 512
#define HID 1024
#define NHEADS 12
#define HSZ 64
#define NPROJ 1536
#define NEG_INF 1000000000000.0f

typedef __attribute__((ext_vector_type(4))) float f32x4;
typedef __attribute__((ext_vector_type(8))) __bf16 bf16x8;
typedef __attribute__((ext_vector_type(4))) unsigned short us4;

typedef __attribute__((address_space(1))) unsigned char gu8;
typedef __attribute__((address_space(3))) unsigned char lu8;

static __device__ __forceinline__ void gld16(const void* g, void* l) {
  __builtin_amdgcn_global_load_lds((gu8*)(g), (lu8*)(l), 16, 0, 0);
}

static __device__ __forceinline__ unsigned short f2bf(float f) {
  union { float f; unsigned u; } x; x.f = f;
  unsigned r = x.u + 0x7fffu + ((x.u >> 16) & 1u);
  return (unsigned short)(r >> 16);
}

// ---- merged prep: [0,64) sincos table | [64,4160) x->bf16 | [4160,5696) W^T->bf16
__global__ __launch_bounds__(256) void k_prep(
    const float4* __restrict__ x, const float* __restrict__ W,
    float2* __restrict__ tab, us4* __restrict__ xb, unsigned short* __restrict__ wbt) {
  __shared__ float t[32][33];
  const int bid = blockIdx.x;
  const int tid = threadIdx.x;
  if (bid < 64) {
    int tt = bid * 256 + tid;
    int s = tt >> 5, i = tt & 31;
    float rate = powf(10000.0f, -(float)i / 32.0f);
    float sv, cv;
    sincosf((float)s * rate, &sv, &cv);
    tab[tt] = make_float2(sv, cv);
  } else if (bid < 64 + 4096) {
    int i = (bid - 64) * 256 + tid;
    float4 v = x[i];
    us4 o;
    o[0] = f2bf(v.x); o[1] = f2bf(v.y); o[2] = f2bf(v.z); o[3] = f2bf(v.w);
    xb[i] = o;
  } else {
    int flat = bid - (64 + 4096);
    int n0 = (flat % 48) * 32, k0 = (flat / 48) * 32;
    int tx = tid & 31, ty = tid >> 5;
#pragma unroll
    for (int i = 0; i < 4; ++i)
      t[ty + i * 8][tx] = W[(k0 + ty + i * 8) * NPROJ + n0 + tx];
    __syncthreads();
#pragma unroll
    for (int i = 0; i < 4; ++i)
      wbt[(n0 + ty + i * 8) * HID + (k0 + tx)] = f2bf(t[tx][ty + i * 8]);
  }
}

// ---- GEMM1 (R5-exact): M=128,N=96,BK=64; grid (32,16); dbuf + counted vmcnt.
__global__ __launch_bounds__(256) void k_proj(
    const unsigned short* __restrict__ xb, const unsigned short* __restrict__ wbt,
    const float* __restrict__ bias, const float2* __restrict__ tab,
    unsigned short* __restrict__ qo, unsigned short* __restrict__ ko) {
  __shared__ __align__(16) unsigned short lA[2][128 * 64];
  __shared__ __align__(16) unsigned short lB[2][96 * 64];
  const int tid = threadIdx.x;
  const int lane = tid & 63, w = tid >> 6;
  const int wm = w >> 1, wn = w & 1;
  const int m0 = blockIdx.x * 128, n0 = blockIdx.y * 96;

  const char* aptr[4]; const char* bptr[3];
  int adst[4], bdst[3];
#pragma unroll
  for (int c = 0; c < 4; ++c) {
    int lin = (w * 4 + c) * 1024 + lane * 16;
    int row = lin >> 7, cb = lin & 127;
    aptr[c] = (const char*)(xb + (size_t)(m0 + row) * HID) + (cb ^ ((row & 7) << 4));
    adst[c] = (w * 4 + c) * 1024;
  }
#pragma unroll
  for (int c = 0; c < 3; ++c) {
    int lin = (w * 3 + c) * 1024 + lane * 16;
    int row = lin >> 7, cb = lin & 127;
    bptr[c] = (const char*)(wbt + (size_t)(n0 + row) * HID) + (cb ^ ((row & 7) << 4));
    bdst[c] = (w * 3 + c) * 1024;
  }

  f32x4 acc[3][4];
#pragma unroll
  for (int a = 0; a < 3; ++a)
#pragma unroll
    for (int b = 0; b < 4; ++b)
      acc[a][b] = (f32x4)(0.0f);

#define STAGE(buf, kt)                                                      \
  do {                                                                      \
    _Pragma("unroll") for (int c = 0; c < 4; ++c)                           \
        gld16(aptr[c] + (kt) * 128, (char*)(&lA[(buf)][0]) + adst[c]);      \
    _Pragma("unroll") for (int c = 0; c < 3; ++c)                           \
        gld16(bptr[c] + (kt) * 128, (char*)(&lB[(buf)][0]) + bdst[c]);      \
  } while (0)

  __builtin_amdgcn_sched_barrier(0);
  STAGE(0, 0);

  for (int kt = 0; kt < 16; ++kt) {
    const int cur = kt & 1;
    if (kt < 15) {
      STAGE(cur ^ 1, kt + 1);
      asm volatile("s_waitcnt vmcnt(7)" ::: "memory");
    } else {
      asm volatile("s_waitcnt vmcnt(0)" ::: "memory");
    }
    __builtin_amdgcn_s_barrier();
#pragma unroll
    for (int ks = 0; ks < 2; ++ks) {
      bf16x8 af[3], bf[4];
      const int kb = ks * 64 + (lane >> 4) * 16;
#pragma unroll
      for (int a = 0; a < 3; ++a) {
        int row = wn * 48 + a * 16 + (lane & 15);
        af[a] = *(const bf16x8*)((const char*)(&lB[cur][0]) + row * 128 + (kb ^ ((row & 7) << 4)));
      }
#pragma unroll
      for (int b = 0; b < 4; ++b) {
        int row = wm * 64 + b * 16 + (lane & 15);
        bf[b] = *(const bf16x8*)((const char*)(&lA[cur][0]) + row * 128 + (kb ^ ((row & 7) << 4)));
      }
#pragma unroll
      for (int a = 0; a < 3; ++a)
#pragma unroll
        for (int b = 0; b < 4; ++b)
          acc[a][b] = __builtin_amdgcn_mfma_f32_16x16x32_bf16(af[a], bf[b], acc[a][b], 0, 0, 0);
    }
    asm volatile("s_waitcnt lgkmcnt(0)" ::: "memory");
    __builtin_amdgcn_s_barrier();
  }
#undef STAGE
  __builtin_amdgcn_sched_barrier(0);

#pragma unroll
  for (int a = 0; a < 3; ++a) {
    const int nq = n0 + wn * 48 + a * 16 + (lane >> 4) * 4;
    const float4 bv = *(const float4*)(bias + nq);
    const int d = nq & 63;
    const int h = nq >> 7;
    unsigned short* base = ((nq >> 6) & 1) ? ko : qo;
#pragma unroll
    for (int b = 0; b < 4; ++b) {
      const int mrow = m0 + wm * 64 + b * 16 + (lane & 15);
      const int s = mrow & (SS - 1);
      const int bidx = mrow >> 9;
      const float2* tp = tab + s * 32 + (d & 31);
      const float4 ta = *(const float4*)(tp);
      const float4 tb = *(const float4*)(tp + 2);
      float v0 = acc[a][b][0] + bv.x;
      float v1 = acc[a][b][1] + bv.y;
      float v2 = acc[a][b][2] + bv.z;
      float v3 = acc[a][b][3] + bv.w;
      float o0 = v0 * ta.y - v1 * ta.x;
      float o1 = v1 * ta.w + v0 * ta.z;
      float o2 = v2 * tb.y - v3 * tb.x;
      float o3 = v3 * tb.w + v2 * tb.z;
      us4 pk;
      pk[0] = f2bf(o0); pk[1] = f2bf(o1); pk[2] = f2bf(o2); pk[3] = f2bf(o3);
      *(us4*)(base + ((size_t)(bidx * NHEADS + h) * SS + s) * HSZ + d) = pk;
    }
  }
}

// ---- GEMM2: 128m x 256n strip per block. q-frags loaded ONCE (register-resident),
// 2 n-tiles looped. Re-reads: q 2x + k 2x = 25MB (was 50MB). Causal skip kept.
__global__ __launch_bounds__(256) void k_logits(
    const unsigned short* __restrict__ q, const unsigned short* __restrict__ kk,
    const float* __restrict__ mask, float* __restrict__ out) {
  const int tid = threadIdx.x;
  const int lane = tid & 63, w = tid >> 6;
  const int bh = blockIdx.y;
  const int b = bh / NHEADS;
  const int mt = blockIdx.x >> 1, nh = blockIdx.x & 1;
  const int m0 = mt * 128;
  const char* qbase = (const char*)(q + (size_t)bh * SS * HSZ);
  const char* kbase = (const char*)(kk + (size_t)bh * SS * HSZ);

  int mrow[4];
#pragma unroll
  for (int i = 0; i < 4; ++i)
    mrow[i] = m0 + (w >> 1) * 64 + i * 16 + (lane & 15);

  // q fragments: loaded once, reused across both n-tiles
  bf16x8 qf[2][4];
#pragma unroll
  for (int ks = 0; ks < 2; ++ks) {
    const int kboff = ks * 64 + (lane >> 4) * 16;
#pragma unroll
    for (int i = 0; i < 4; ++i)
      qf[ks][i] = *(const bf16x8*)(qbase + (size_t)mrow[i] * 128 + kboff);
  }

#pragma unroll
  for (int nt2 = 0; nt2 < 2; ++nt2) {
    const int n0 = (nh * 2 + nt2) * 128;
    const bool full_masked = (n0 + 128 <= m0);

    f32x4 acc[4][4];  // [ni][mi]
#pragma unroll
    for (int a = 0; a < 4; ++a)
#pragma unroll
      for (int bb = 0; bb < 4; ++bb)
        acc[a][bb] = (f32x4)(0.0f);

    if (!full_masked) {
#pragma unroll
      for (int ks = 0; ks < 2; ++ks) {
        const int kboff = ks * 64 + (lane >> 4) * 16;
        bf16x8 kf[4];
#pragma unroll
        for (int i = 0; i < 4; ++i) {
          const int nrow = n0 + (w & 1) * 64 + i * 16 + (lane & 15);
          kf[i] = *(const bf16x8*)(kbase + (size_t)nrow * 128 + kboff);
        }
#pragma unroll
        for (int ni = 0; ni < 4; ++ni)
#pragma unroll
          for (int mi = 0; mi < 4; ++mi)
            acc[ni][mi] = __builtin_amdgcn_mfma_f32_16x16x32_bf16(kf[ni], qf[ks][mi], acc[ni][mi], 0, 0, 0);
      }
    }

#pragma unroll
    for (int mi = 0; mi < 4; ++mi) {
      const int m = mrow[mi];
      const float mr = mask[b * SS + m];
      float* orow = out + ((size_t)bh * SS + m) * SS;
#pragma unroll
      for (int ni = 0; ni < 4; ++ni) {
        const int nb = n0 + (w & 1) * 64 + ni * 16 + (lane >> 4) * 4;
        const float4 mc = *(const float4*)(mask + b * SS + nb);
        f32x4 res;
#pragma unroll
        for (int r = 0; r < 4; ++r) {
          float v = acc[ni][mi][r];
          const float mcv = (r == 0) ? mc.x : (r == 1) ? mc.y : (r == 2) ? mc.z : mc.w;
          v = v * mr - NEG_INF * (1.0f - mr);
          v = v * mcv - NEG_INF * (1.0f - mcv);
          if (m > nb + r) v -= NEG_INF;
          res[r] = v * 0.125f;
        }
        *(f32x4*)(orow + nb) = res;
      }
    }
  }
}

extern "C" void kernel_launch(void* const* d_in, const int* in_sizes, int n_in,
                              void* d_out, int out_size, void* d_ws, size_t ws_size,
                              hipStream_t stream) {
  const float* x = (const float*)d_in[0];
  const float* mask = (const float*)d_in[1];
  const float* W = (const float*)d_in[2];
  const float* bias = (const float*)d_in[3];
  float* out = (float*)d_out;

  char* ws = (char*)d_ws;
  float2* tab = (float2*)ws;                                               // 128 KB
  unsigned short* xb = (unsigned short*)(ws + 131072);                     // 8 MB
  unsigned short* wbt = (unsigned short*)(ws + 131072 + 8388608);          // 3 MB
  unsigned short* qo = (unsigned short*)(ws + 131072 + 8388608 + 3145728); // 6.29 MB
  unsigned short* ko = (unsigned short*)(ws + 131072 + 8388608 + 3145728 + 6291456);

  k_prep<<<dim3(64 + 4096 + 1536), dim3(256), 0, stream>>>(
      (const float4*)x, W, tab, (us4*)xb, wbt);
  k_proj<<<dim3(32, 16), dim3(256), 0, stream>>>(xb, wbt, bias, tab, qo, ko);
  k_logits<<<dim3(8, 96), dim3(256), 0, stream>>>(qo, ko, mask, out);
}